// Round 20
// baseline (92.426 us; speedup 1.0000x reference)
//
#include <hip/hip_runtime.h>

#define HW 4096
#define NC 96
#define NB 4
#define MID 24
#define NOUT 256
#define BEPS 1e-5f
#define SCALE2E 0.14724920341279385f  // (1/sqrt(96)) * log2(e) — exp2-folded

typedef unsigned short u16;
typedef short bf16x8 __attribute__((ext_vector_type(8)));
typedef unsigned short u16x8 __attribute__((ext_vector_type(8)));
typedef float f32x16 __attribute__((ext_vector_type(16)));

__device__ __forceinline__ u16 bfh(float x) {
  unsigned u = __float_as_uint(x);
  return (u16)((u + 0x7FFFu + ((u >> 16) & 1u)) >> 16);  // RNE bf16
}

// ---------------------------------------------------------------------------
// Prep (r19 known-good + 1-thread counter zero): pr = Wr*rgb, pd = Wd*dep;
// psum fp32; bf16 hi fragment-order operands written directly (no LDS).
// grid (HW/64, NB, 3), block 256 = 4 waves x 8 o x 64 n.
// ---------------------------------------------------------------------------
__launch_bounds__(256)
__global__ void k_prep(const float* __restrict__ rgb, const float* __restrict__ dep,
                       const float* __restrict__ Wr, const float* __restrict__ Wd,
                       float* __restrict__ psum, u16* __restrict__ prF, u16* __restrict__ pdF,
                       int* __restrict__ counter) {
  const int tid = threadIdx.x;
  const int lane = tid & 63;
  const int og = __builtin_amdgcn_readfirstlane(tid >> 6);   // wave-uniform o-group
  const int b = blockIdx.y, q = blockIdx.z;
  const int n = blockIdx.x * 64 + lane;
  const int obase = q * 32 + og * 8;

  if (blockIdx.x == 0 && blockIdx.y == 0 && blockIdx.z == 0 && tid == 0)
    *counter = 0;   // no hipMemsetAsync (r15 lesson: ~40µs/fill dispatch)

  float ar[8], ad[8];
  #pragma unroll
  for (int o = 0; o < 8; ++o) { ar[o] = 0.f; ad[o] = 0.f; }

  const float* rb = rgb + (size_t)b * NC * HW + n;
  const float* db = dep + (size_t)b * NC * HW + n;
  #pragma unroll 4
  for (int c = 0; c < NC; ++c) {
    float xr = rb[(size_t)c * HW];
    float xd = db[(size_t)c * HW];
    #pragma unroll
    for (int o = 0; o < 8; ++o) {
      float wr = Wr[(obase + o) * NC + c];   // uniform -> s_load
      float wd = Wd[(obase + o) * NC + c];
      ar[o] = fmaf(wr, xr, ar[o]);
      ad[o] = fmaf(wd, xd, ad[o]);
    }
  }

  // psum (fp32, coalesced 256B per o per wave)
  #pragma unroll
  for (int o = 0; o < 8; ++o)
    psum[((size_t)b * NC + obase + o) * HW + n] = ar[o] + ad[o];

  // direct fragment-order bf16 writes (one 16B chunk per thread per array)
  const int c8 = q * 4 + og;            // 0..11
  const int ks = c8 >> 1, khalf = c8 & 1;
  const int tile = n >> 5;
  const size_t off = (size_t)b * HW * 96
                   + ((size_t)(tile * 6 + ks) << 9) + ((khalf * 32 + (n & 31)) << 3);
  u16x8 vr, vd;
  #pragma unroll
  for (int o = 0; o < 8; ++o) { vr[o] = bfh(ar[o]); vd[o] = bfh(ad[o]); }
  *(u16x8*)(prF + off) = vr;
  *(u16x8*)(pdF + off) = vd;
}

// ---------------------------------------------------------------------------
// MFMA energy pass — r19 measured-best (83.5µs total config), unchanged:
// A-pinned (12 frags upfront), (256,2), partial arrays, fused nlz in PASS 1,
// raw v_exp_f32 via __builtin_amdgcn_exp2f with folded SCALE2E.
// wave tile 64x64 (acc[2][2]=64 AGPR), block 128x128, grid (32,32,NB),
// XCD-chunked swizzle. 1-term bf16 (gate err 1 ULP vs 4.4 ULP budget).
// PASS 0: A=pr(n) B=pd(m): zpart[by][b][m] = colsum_n exp2(e*S2)
// PASS 1: A=pd(m) B=pr(n): nlz = -log2(Z) from 32 zpart partials (fused);
//         spart[by][b][n] = colsum_m exp2(e*S2 + nlz[m])
// ---------------------------------------------------------------------------
template <int PASS>
__launch_bounds__(256, 2)
__global__ void k_energy(const u16* __restrict__ At, const u16* __restrict__ Bt,
                         const float* __restrict__ zin, float* __restrict__ part) {
  __shared__ float red[2][128];
  __shared__ float nlzL[128];
  const int tid = threadIdx.x;
  const int lane = tid & 63, wid = tid >> 6;
  const int wA = wid >> 1, wB = wid & 1;
  const int b = blockIdx.z;
  const int flat = blockIdx.y * 32 + blockIdx.x;   // 0..1023
  const int by = (flat & 7) * 4 + ((flat >> 3) & 3);
  const int bx = flat >> 5;
  const int a0 = by * 128;
  const int c0 = bx * 128;
  const u16* Ab = At + (size_t)b * HW * 96;
  const u16* Bb = Bt + (size_t)b * HW * 96;
  const int tA0 = by * 4 + wA * 2;   // 2 A-tiles of 32 rows
  const int tB0 = bx * 4 + wB * 2;   // 2 B-tiles of 32 cols

  if (PASS) {  // fused nlz: sum 32 zpart partials for this block's A-rows (m)
    if (tid < 128) {
      float s = 0.f;
      #pragma unroll
      for (int t = 0; t < 32; ++t) s += zin[((size_t)t * NB + b) * HW + a0 + tid];
      nlzL[tid] = -__log2f(s);
    }
    __syncthreads();
  }

  // pin A-hi fragments in registers (48 VGPR), deep in-flight queue
  bf16x8 Ah[2][6];
  #pragma unroll
  for (int ta = 0; ta < 2; ++ta)
    #pragma unroll
    for (int ks = 0; ks < 6; ++ks)
      Ah[ta][ks] = *(const bf16x8*)(Ab + (((tA0 + ta) * 6 + ks) << 9) + (lane << 3));

  f32x16 acc[2][2];
  #pragma unroll
  for (int ta = 0; ta < 2; ++ta)
    #pragma unroll
    for (int tb = 0; tb < 2; ++tb)
      #pragma unroll
      for (int q = 0; q < 16; ++q) acc[ta][tb][q] = 0.f;

  #pragma unroll
  for (int ks = 0; ks < 6; ++ks) {
    #pragma unroll
    for (int tb = 0; tb < 2; ++tb) {
      bf16x8 bh = *(const bf16x8*)(Bb + (((tB0 + tb) * 6 + ks) << 9) + (lane << 3));
      #pragma unroll
      for (int ta = 0; ta < 2; ++ta)
        acc[ta][tb] = __builtin_amdgcn_mfma_f32_32x32x16_bf16(Ah[ta][ks], bh, acc[ta][tb], 0, 0, 0);
    }
  }

  // exp2 + column sums. C/D: col=lane&31, row=(q&3)+8*(q>>2)+4*(lane>>5)
  float csum[2] = {0.f, 0.f};
  float nlzv = 0.f;
  if (PASS) nlzv = nlzL[wA * 64 + lane];
  #pragma unroll
  for (int ta = 0; ta < 2; ++ta) {
    #pragma unroll
    for (int q = 0; q < 16; ++q) {
      float bias = 0.f;
      if (PASS) {
        int src = ta * 32 + (q & 3) + 8 * (q >> 2) + 4 * (lane >> 5);
        bias = __shfl(nlzv, src, 64);
      }
      #pragma unroll
      for (int tb = 0; tb < 2; ++tb)
        csum[tb] += __builtin_amdgcn_exp2f(fmaf(acc[ta][tb][q], SCALE2E, bias));
    }
  }
  #pragma unroll
  for (int tb = 0; tb < 2; ++tb) csum[tb] += __shfl_xor(csum[tb], 32, 64);
  if (lane < 32) {
    #pragma unroll
    for (int tb = 0; tb < 2; ++tb) red[wA][wB * 64 + tb * 32 + lane] = csum[tb];
  }
  __syncthreads();
  if (tid < 128)
    part[((size_t)by * NB + b) * HW + c0 + tid] = red[0][tid] + red[1][tid];
}

// ---------------------------------------------------------------------------
__global__ void k_sred(const float* __restrict__ spart, float* __restrict__ sv) {
  int idx = blockIdx.x * 256 + threadIdx.x;   // over NB*HW
  float a = 0.f;
  #pragma unroll
  for (int t = 0; t < 32; ++t) a += spart[(size_t)t * (NB * HW) + idx];
  sv[idx] = a;
}

// ---------------------------------------------------------------------------
// gap[b,c] = (1/HW)*[ sum_n psum[c,n]*s[n] + sum_n (rgb+dep)[c,n] ]
// + completion-counter MLP fusion (re-applied now that the exp2f-libm
// confound is removed; mechanism correctness validated r15-r18).
// ---------------------------------------------------------------------------
__launch_bounds__(256)
__global__ void k_gap(const float* __restrict__ psum, const float* __restrict__ rgb,
                      const float* __restrict__ dep, const float* __restrict__ sv,
                      float* __restrict__ gapb, int* __restrict__ counter,
                      const float* __restrict__ Wm1, const float* __restrict__ g1,
                      const float* __restrict__ b1,
                      const float* __restrict__ Wm2, const float* __restrict__ g2,
                      const float* __restrict__ b2, float* __restrict__ out) {
  const int c = blockIdx.x, b = blockIdx.y;
  const int tid = threadIdx.x;
  const size_t off = ((size_t)b * NC + c) * HW;
  const float* pp = psum + off;
  const float* rp = rgb + off;
  const float* dp = dep + off;
  const float* sp = sv + (size_t)b * HW;
  float a1 = 0.f, a2 = 0.f;
  for (int n = tid * 4; n < HW; n += 1024) {
    float4 p = *(const float4*)&pp[n];
    float4 s4 = *(const float4*)&sp[n];
    float4 r4 = *(const float4*)&rp[n];
    float4 d4 = *(const float4*)&dp[n];
    a1 += p.x * s4.x + p.y * s4.y + p.z * s4.z + p.w * s4.w;
    a2 += (r4.x + d4.x) + (r4.y + d4.y) + (r4.z + d4.z) + (r4.w + d4.w);
  }
  #pragma unroll
  for (int o = 32; o > 0; o >>= 1) {
    a1 += __shfl_down(a1, o, 64);
    a2 += __shfl_down(a2, o, 64);
  }
  __shared__ float r1[4], r2[4];
  __shared__ int isLast;
  const int wv = tid >> 6;
  if ((tid & 63) == 0) { r1[wv] = a1; r2[wv] = a2; }
  __syncthreads();
  if (tid == 0) {
    float t1 = r1[0] + r1[1] + r1[2] + r1[3];
    float t2 = r2[0] + r2[1] + r2[2] + r2[3];
    gapb[b * NC + c] = (t1 + t2) * (1.0f / HW);
    __threadfence();
    int old = atomicAdd(counter, 1);
    isLast = (old == NC * NB - 1);
  }
  __syncthreads();
  if (!isLast) return;

  // ---- last block: tiny MLP + BN(batch=4) + ReLU ----
  __shared__ float gl[NB * NC];
  __shared__ float h[NB * MID];
  __shared__ float h1r[NB * MID];
  __shared__ float h2[NB * NOUT];
  __threadfence();
  for (int i = tid; i < NB * NC; i += 256)
    gl[i] = atomicAdd(&gapb[i], 0.0f);     // device-scope RMW read: fresh value
  __syncthreads();

  if (tid < NB * MID) {
    int bb2 = tid / MID, j = tid % MID;
    float acc = 0.f;
    #pragma unroll
    for (int cc = 0; cc < NC; ++cc) acc += gl[bb2 * NC + cc] * Wm1[j * NC + cc];
    h[bb2 * MID + j] = acc;
  }
  __syncthreads();

  if (tid < MID) {
    float x0 = h[0 * MID + tid], x1 = h[1 * MID + tid];
    float x2 = h[2 * MID + tid], x3 = h[3 * MID + tid];
    float mu = 0.25f * (x0 + x1 + x2 + x3);
    float d0 = x0 - mu, d1 = x1 - mu, d2 = x2 - mu, d3 = x3 - mu;
    float v = 0.25f * (d0 * d0 + d1 * d1 + d2 * d2 + d3 * d3);
    float sc = g1[tid] * rsqrtf(v + BEPS);
    float bb = b1[tid];
    h1r[0 * MID + tid] = fmaxf(d0 * sc + bb, 0.f);
    h1r[1 * MID + tid] = fmaxf(d1 * sc + bb, 0.f);
    h1r[2 * MID + tid] = fmaxf(d2 * sc + bb, 0.f);
    h1r[3 * MID + tid] = fmaxf(d3 * sc + bb, 0.f);
  }
  __syncthreads();

  for (int idx = tid; idx < NB * NOUT; idx += 256) {
    int bb2 = idx >> 8, o = idx & 255;
    float acc = 0.f;
    #pragma unroll
    for (int j = 0; j < MID; ++j) acc += h1r[bb2 * MID + j] * Wm2[o * MID + j];
    h2[bb2 * NOUT + o] = acc;
  }
  __syncthreads();

  if (tid < NOUT) {
    float x0 = h2[0 * NOUT + tid], x1 = h2[1 * NOUT + tid];
    float x2 = h2[2 * NOUT + tid], x3 = h2[3 * NOUT + tid];
    float mu = 0.25f * (x0 + x1 + x2 + x3);
    float d0 = x0 - mu, d1 = x1 - mu, d2 = x2 - mu, d3 = x3 - mu;
    float v = 0.25f * (d0 * d0 + d1 * d1 + d2 * d2 + d3 * d3);
    float sc = g2[tid] * rsqrtf(v + BEPS);
    float bb = b2[tid];
    out[0 * NOUT + tid] = fmaxf(d0 * sc + bb, 0.f);
    out[1 * NOUT + tid] = fmaxf(d1 * sc + bb, 0.f);
    out[2 * NOUT + tid] = fmaxf(d2 * sc + bb, 0.f);
    out[3 * NOUT + tid] = fmaxf(d3 * sc + bb, 0.f);
  }
}

// ---------------------------------------------------------------------------
extern "C" void kernel_launch(void* const* d_in, const int* in_sizes, int n_in,
                              void* d_out, int out_size, void* d_ws, size_t ws_size,
                              hipStream_t stream) {
  const float* rgb   = (const float*)d_in[0];
  const float* dep   = (const float*)d_in[1];
  const float* Wd    = (const float*)d_in[2];
  const float* Wr    = (const float*)d_in[3];
  const float* Wm1   = (const float*)d_in[4];
  const float* bn1_g = (const float*)d_in[5];
  const float* bn1_b = (const float*)d_in[6];
  const float* Wm2   = (const float*)d_in[7];
  const float* bn2_g = (const float*)d_in[8];
  const float* bn2_b = (const float*)d_in[9];
  float* out = (float*)d_out;

  char* w = (char*)d_ws;
  u16* prF = (u16*)w;             w += (size_t)NB * HW * 96 * 2;    // 3.15 MB (hi only)
  u16* pdF = (u16*)w;             w += (size_t)NB * HW * 96 * 2;    // 3.15 MB
  float* psum  = (float*)w;       w += (size_t)NB * NC * HW * 4;    // 6.3 MB
  float* zpart = (float*)w;       w += (size_t)32 * NB * HW * 4;    // 2 MB
  float* spart = (float*)w;       w += (size_t)32 * NB * HW * 4;    // 2 MB
  float* sv    = (float*)w;       w += (size_t)NB * HW * 4;
  float* gap   = (float*)w;       w += (size_t)NB * NC * 4;
  int* counter = (int*)w;         w += 64;

  k_prep<<<dim3(HW / 64, NB, 3), 256, 0, stream>>>(rgb, dep, Wr, Wd, psum, prF, pdF, counter);
  k_energy<0><<<dim3(32, 32, NB), 256, 0, stream>>>(prF, pdF, nullptr, zpart);
  k_energy<1><<<dim3(32, 32, NB), 256, 0, stream>>>(pdF, prF, zpart, spart);
  k_sred<<<NB * HW / 256, 256, 0, stream>>>(spart, sv);
  k_gap<<<dim3(NC, NB), 256, 0, stream>>>(psum, rgb, dep, sv, gap, counter,
                                          Wm1, bn1_g, bn1_b, Wm2, bn2_g, bn2_b, out);
}

// Round 21
// 82.734 us; speedup vs baseline: 1.1172x; 1.1172x over previous
//
#include <hip/hip_runtime.h>

#define HW 4096
#define NC 96
#define NB 4
#define MID 24
#define NOUT 256
#define BEPS 1e-5f
#define SCALE2E 0.14724920341279385f  // (1/sqrt(96)) * log2(e) — exp2-folded

typedef unsigned short u16;
typedef short bf16x8 __attribute__((ext_vector_type(8)));
typedef unsigned short u16x8 __attribute__((ext_vector_type(8)));
typedef float f32x16 __attribute__((ext_vector_type(16)));

__device__ __forceinline__ u16 bfh(float x) {
  unsigned u = __float_as_uint(x);
  return (u16)((u + 0x7FFFu + ((u >> 16) & 1u)) >> 16);  // RNE bf16
}

// ---------------------------------------------------------------------------
// Prep (r11 known-good, byte-identical): pr = Wr*rgb, pd = Wd*dep; psum fp32;
// bf16 hi fragment-order operands written directly (no LDS).
// grid (HW/64, NB, 3), block 256 = 4 waves x 8 o x 64 n.
// ---------------------------------------------------------------------------
__launch_bounds__(256)
__global__ void k_prep(const float* __restrict__ rgb, const float* __restrict__ dep,
                       const float* __restrict__ Wr, const float* __restrict__ Wd,
                       float* __restrict__ psum, u16* __restrict__ prF, u16* __restrict__ pdF) {
  const int tid = threadIdx.x;
  const int lane = tid & 63;
  const int og = __builtin_amdgcn_readfirstlane(tid >> 6);   // wave-uniform o-group
  const int b = blockIdx.y, q = blockIdx.z;
  const int n = blockIdx.x * 64 + lane;
  const int obase = q * 32 + og * 8;

  float ar[8], ad[8];
  #pragma unroll
  for (int o = 0; o < 8; ++o) { ar[o] = 0.f; ad[o] = 0.f; }

  const float* rb = rgb + (size_t)b * NC * HW + n;
  const float* db = dep + (size_t)b * NC * HW + n;
  #pragma unroll 4
  for (int c = 0; c < NC; ++c) {
    float xr = rb[(size_t)c * HW];
    float xd = db[(size_t)c * HW];
    #pragma unroll
    for (int o = 0; o < 8; ++o) {
      float wr = Wr[(obase + o) * NC + c];   // uniform -> s_load
      float wd = Wd[(obase + o) * NC + c];
      ar[o] = fmaf(wr, xr, ar[o]);
      ad[o] = fmaf(wd, xd, ad[o]);
    }
  }

  // psum (fp32, coalesced 256B per o per wave)
  #pragma unroll
  for (int o = 0; o < 8; ++o)
    psum[((size_t)b * NC + obase + o) * HW + n] = ar[o] + ad[o];

  // direct fragment-order bf16 writes (one 16B chunk per thread per array)
  const int c8 = q * 4 + og;            // 0..11
  const int ks = c8 >> 1, khalf = c8 & 1;
  const int tile = n >> 5;
  const size_t off = (size_t)b * HW * 96
                   + ((size_t)(tile * 6 + ks) << 9) + ((khalf * 32 + (n & 31)) << 3);
  u16x8 vr, vd;
  #pragma unroll
  for (int o = 0; o < 8; ++o) { vr[o] = bfh(ar[o]); vd[o] = bfh(ad[o]); }
  *(u16x8*)(prF + off) = vr;
  *(u16x8*)(pdF + off) = vd;
}

// ---------------------------------------------------------------------------
// MFMA energy pass — r19 measured-best (83.5µs total config):
// A-pinned (12 frags upfront), (256,2), partial arrays, fused nlz in PASS 1,
// raw v_exp_f32 via __builtin_amdgcn_exp2f with folded SCALE2E.
// wave tile 64x64 (acc[2][2]=64 AGPR), block 128x128, grid (32,32,NB),
// XCD-chunked swizzle. 1-term bf16 (gate err 1 ULP vs 4.4 ULP budget).
// PASS 0: A=pr(n) B=pd(m): zpart[by][b][m] = colsum_n exp2(e*S2)
// PASS 1: A=pd(m) B=pr(n): nlz = -log2(Z) from 32 zpart partials (fused);
//         spart[by][b][n] = colsum_m exp2(e*S2 + nlz[m])
// ---------------------------------------------------------------------------
template <int PASS>
__launch_bounds__(256, 2)
__global__ void k_energy(const u16* __restrict__ At, const u16* __restrict__ Bt,
                         const float* __restrict__ zin, float* __restrict__ part) {
  __shared__ float red[2][128];
  __shared__ float nlzL[128];
  const int tid = threadIdx.x;
  const int lane = tid & 63, wid = tid >> 6;
  const int wA = wid >> 1, wB = wid & 1;
  const int b = blockIdx.z;
  const int flat = blockIdx.y * 32 + blockIdx.x;   // 0..1023
  const int by = (flat & 7) * 4 + ((flat >> 3) & 3);
  const int bx = flat >> 5;
  const int a0 = by * 128;
  const int c0 = bx * 128;
  const u16* Ab = At + (size_t)b * HW * 96;
  const u16* Bb = Bt + (size_t)b * HW * 96;
  const int tA0 = by * 4 + wA * 2;   // 2 A-tiles of 32 rows
  const int tB0 = bx * 4 + wB * 2;   // 2 B-tiles of 32 cols

  if (PASS) {  // fused nlz: sum 32 zpart partials for this block's A-rows (m)
    if (tid < 128) {
      float s = 0.f;
      #pragma unroll
      for (int t = 0; t < 32; ++t) s += zin[((size_t)t * NB + b) * HW + a0 + tid];
      nlzL[tid] = -__log2f(s);
    }
    __syncthreads();
  }

  // pin A-hi fragments in registers (48 VGPR), deep in-flight queue
  bf16x8 Ah[2][6];
  #pragma unroll
  for (int ta = 0; ta < 2; ++ta)
    #pragma unroll
    for (int ks = 0; ks < 6; ++ks)
      Ah[ta][ks] = *(const bf16x8*)(Ab + (((tA0 + ta) * 6 + ks) << 9) + (lane << 3));

  f32x16 acc[2][2];
  #pragma unroll
  for (int ta = 0; ta < 2; ++ta)
    #pragma unroll
    for (int tb = 0; tb < 2; ++tb)
      #pragma unroll
      for (int q = 0; q < 16; ++q) acc[ta][tb][q] = 0.f;

  #pragma unroll
  for (int ks = 0; ks < 6; ++ks) {
    #pragma unroll
    for (int tb = 0; tb < 2; ++tb) {
      bf16x8 bh = *(const bf16x8*)(Bb + (((tB0 + tb) * 6 + ks) << 9) + (lane << 3));
      #pragma unroll
      for (int ta = 0; ta < 2; ++ta)
        acc[ta][tb] = __builtin_amdgcn_mfma_f32_32x32x16_bf16(Ah[ta][ks], bh, acc[ta][tb], 0, 0, 0);
    }
  }

  // exp2 + column sums. C/D: col=lane&31, row=(q&3)+8*(q>>2)+4*(lane>>5)
  float csum[2] = {0.f, 0.f};
  float nlzv = 0.f;
  if (PASS) nlzv = nlzL[wA * 64 + lane];
  #pragma unroll
  for (int ta = 0; ta < 2; ++ta) {
    #pragma unroll
    for (int q = 0; q < 16; ++q) {
      float bias = 0.f;
      if (PASS) {
        int src = ta * 32 + (q & 3) + 8 * (q >> 2) + 4 * (lane >> 5);
        bias = __shfl(nlzv, src, 64);
      }
      #pragma unroll
      for (int tb = 0; tb < 2; ++tb)
        csum[tb] += __builtin_amdgcn_exp2f(fmaf(acc[ta][tb][q], SCALE2E, bias));
    }
  }
  #pragma unroll
  for (int tb = 0; tb < 2; ++tb) csum[tb] += __shfl_xor(csum[tb], 32, 64);
  if (lane < 32) {
    #pragma unroll
    for (int tb = 0; tb < 2; ++tb) red[wA][wB * 64 + tb * 32 + lane] = csum[tb];
  }
  __syncthreads();
  if (tid < 128)
    part[((size_t)by * NB + b) * HW + c0 + tid] = red[0][tid] + red[1][tid];
}

// ---------------------------------------------------------------------------
__global__ void k_sred(const float* __restrict__ spart, float* __restrict__ sv) {
  int idx = blockIdx.x * 256 + threadIdx.x;   // over NB*HW
  float a = 0.f;
  #pragma unroll
  for (int t = 0; t < 32; ++t) a += spart[(size_t)t * (NB * HW) + idx];
  sv[idx] = a;
}

// ---------------------------------------------------------------------------
// gap[b,c] = (1/HW)*[ sum_n psum[c,n]*s[n] + sum_n (rgb+dep)[c,n] ]
// (plain r19 version — counter/fence MLP fusion measured net-negative in r20)
// ---------------------------------------------------------------------------
__launch_bounds__(256)
__global__ void k_gap(const float* __restrict__ psum, const float* __restrict__ rgb,
                      const float* __restrict__ dep, const float* __restrict__ sv,
                      float* __restrict__ gap) {
  const int c = blockIdx.x, b = blockIdx.y;
  const size_t off = ((size_t)b * NC + c) * HW;
  const float* pp = psum + off;
  const float* rp = rgb + off;
  const float* dp = dep + off;
  const float* sp = sv + (size_t)b * HW;
  float a1 = 0.f, a2 = 0.f;
  for (int n = threadIdx.x * 4; n < HW; n += 1024) {
    float4 p = *(const float4*)&pp[n];
    float4 s4 = *(const float4*)&sp[n];
    float4 r4 = *(const float4*)&rp[n];
    float4 d4 = *(const float4*)&dp[n];
    a1 += p.x * s4.x + p.y * s4.y + p.z * s4.z + p.w * s4.w;
    a2 += (r4.x + d4.x) + (r4.y + d4.y) + (r4.z + d4.z) + (r4.w + d4.w);
  }
  #pragma unroll
  for (int o = 32; o > 0; o >>= 1) {
    a1 += __shfl_down(a1, o, 64);
    a2 += __shfl_down(a2, o, 64);
  }
  __shared__ float r1[4], r2[4];
  const int wv = threadIdx.x >> 6;
  if ((threadIdx.x & 63) == 0) { r1[wv] = a1; r2[wv] = a2; }
  __syncthreads();
  if (threadIdx.x == 0) {
    float t1 = r1[0] + r1[1] + r1[2] + r1[3];
    float t2 = r2[0] + r2[1] + r2[2] + r2[3];
    gap[b * NC + c] = (t1 + t2) * (1.0f / HW);
  }
}

// ---------------------------------------------------------------------------
// Tiny MLP + training-mode BatchNorm (over batch of 4) + ReLU, one block.
// ---------------------------------------------------------------------------
__launch_bounds__(256)
__global__ void k_mlp(const float* __restrict__ gap,
                      const float* __restrict__ Wm1, const float* __restrict__ g1,
                      const float* __restrict__ b1,
                      const float* __restrict__ Wm2, const float* __restrict__ g2,
                      const float* __restrict__ b2, float* __restrict__ out) {
  __shared__ float gl[NB * NC];
  __shared__ float h[NB * MID];
  __shared__ float h1r[NB * MID];
  __shared__ float h2[NB * NOUT];
  const int tid = threadIdx.x;
  for (int i = tid; i < NB * NC; i += 256) gl[i] = gap[i];
  __syncthreads();

  if (tid < NB * MID) {
    int b = tid / MID, j = tid % MID;
    float acc = 0.f;
    #pragma unroll
    for (int c = 0; c < NC; ++c) acc += gl[b * NC + c] * Wm1[j * NC + c];
    h[b * MID + j] = acc;
  }
  __syncthreads();

  if (tid < MID) {
    float x0 = h[0 * MID + tid], x1 = h[1 * MID + tid];
    float x2 = h[2 * MID + tid], x3 = h[3 * MID + tid];
    float mu = 0.25f * (x0 + x1 + x2 + x3);
    float d0 = x0 - mu, d1 = x1 - mu, d2 = x2 - mu, d3 = x3 - mu;
    float v = 0.25f * (d0 * d0 + d1 * d1 + d2 * d2 + d3 * d3);
    float sc = g1[tid] * rsqrtf(v + BEPS);
    float bb = b1[tid];
    h1r[0 * MID + tid] = fmaxf(d0 * sc + bb, 0.f);
    h1r[1 * MID + tid] = fmaxf(d1 * sc + bb, 0.f);
    h1r[2 * MID + tid] = fmaxf(d2 * sc + bb, 0.f);
    h1r[3 * MID + tid] = fmaxf(d3 * sc + bb, 0.f);
  }
  __syncthreads();

  for (int idx = tid; idx < NB * NOUT; idx += 256) {
    int b = idx >> 8, o = idx & 255;
    float acc = 0.f;
    #pragma unroll
    for (int j = 0; j < MID; ++j) acc += h1r[b * MID + j] * Wm2[o * MID + j];
    h2[b * NOUT + o] = acc;
  }
  __syncthreads();

  if (tid < NOUT) {
    float x0 = h2[0 * NOUT + tid], x1 = h2[1 * NOUT + tid];
    float x2 = h2[2 * NOUT + tid], x3 = h2[3 * NOUT + tid];
    float mu = 0.25f * (x0 + x1 + x2 + x3);
    float d0 = x0 - mu, d1 = x1 - mu, d2 = x2 - mu, d3 = x3 - mu;
    float v = 0.25f * (d0 * d0 + d1 * d1 + d2 * d2 + d3 * d3);
    float sc = g2[tid] * rsqrtf(v + BEPS);
    float bb = b2[tid];
    out[0 * NOUT + tid] = fmaxf(d0 * sc + bb, 0.f);
    out[1 * NOUT + tid] = fmaxf(d1 * sc + bb, 0.f);
    out[2 * NOUT + tid] = fmaxf(d2 * sc + bb, 0.f);
    out[3 * NOUT + tid] = fmaxf(d3 * sc + bb, 0.f);
  }
}

// ---------------------------------------------------------------------------
extern "C" void kernel_launch(void* const* d_in, const int* in_sizes, int n_in,
                              void* d_out, int out_size, void* d_ws, size_t ws_size,
                              hipStream_t stream) {
  const float* rgb   = (const float*)d_in[0];
  const float* dep   = (const float*)d_in[1];
  const float* Wd    = (const float*)d_in[2];
  const float* Wr    = (const float*)d_in[3];
  const float* Wm1   = (const float*)d_in[4];
  const float* bn1_g = (const float*)d_in[5];
  const float* bn1_b = (const float*)d_in[6];
  const float* Wm2   = (const float*)d_in[7];
  const float* bn2_g = (const float*)d_in[8];
  const float* bn2_b = (const float*)d_in[9];
  float* out = (float*)d_out;

  char* w = (char*)d_ws;
  u16* prF = (u16*)w;             w += (size_t)NB * HW * 96 * 2;    // 3.15 MB (hi only)
  u16* pdF = (u16*)w;             w += (size_t)NB * HW * 96 * 2;    // 3.15 MB
  float* psum  = (float*)w;       w += (size_t)NB * NC * HW * 4;    // 6.3 MB
  float* zpart = (float*)w;       w += (size_t)32 * NB * HW * 4;    // 2 MB
  float* spart = (float*)w;       w += (size_t)32 * NB * HW * 4;    // 2 MB
  float* sv    = (float*)w;       w += (size_t)NB * HW * 4;
  float* gap   = (float*)w;       w += (size_t)NB * NC * 4;

  k_prep<<<dim3(HW / 64, NB, 3), 256, 0, stream>>>(rgb, dep, Wr, Wd, psum, prF, pdF);
  k_energy<0><<<dim3(32, 32, NB), 256, 0, stream>>>(prF, pdF, nullptr, zpart);
  k_energy<1><<<dim3(32, 32, NB), 256, 0, stream>>>(pdF, prF, zpart, spart);
  k_sred<<<NB * HW / 256, 256, 0, stream>>>(spart, sv);
  k_gap<<<dim3(NC, NB), 256, 0, stream>>>(psum, rgb, dep, sv, gap);
  k_mlp<<<1, 256, 0, stream>>>(gap, Wm1, bn1_g, bn1_b, Wm2, bn2_g, bn2_b, out);
}